// Round 4
// baseline (1876.458 us; speedup 1.0000x reference)
//
#include <hip/hip_runtime.h>

#define N_NODES 50000
#define N_EDGES 800000
#define D 128
#define NLAYER 4
#define NGRAPH 128
#define GDIM (5 * D) // 640
#define NSEG ((N_NODES + 63) / 64) // 782 tiles of 64 nodes

// ---------------- CSR build ----------------

__global__ void k_count(const int* __restrict__ edst, int* __restrict__ cnt) {
    int e = blockIdx.x * 256 + threadIdx.x;
    if (e < N_EDGES) atomicAdd(&cnt[edst[e]], 1);
}

__global__ void k_dinv(const int* __restrict__ cnt, float* __restrict__ dinv) {
    int i = blockIdx.x * 256 + threadIdx.x;
    if (i < N_NODES) dinv[i] = 1.f / sqrtf((float)(cnt[i] + 1)); // +1 self-loop
}

// 2-level exclusive scan, chunk = 1024 elements (256 thr x 4)
__global__ void k_scanA(const int* __restrict__ cnt, int* __restrict__ offs,
                        int* __restrict__ chunkSum) {
    __shared__ int lds[256];
    int tid = threadIdx.x;
    int base = blockIdx.x * 1024 + tid * 4;
    int v[4];
    int s = 0;
#pragma unroll
    for (int j = 0; j < 4; ++j) {
        int idx = base + j;
        v[j] = (idx < N_NODES) ? cnt[idx] : 0;
        s += v[j];
    }
    lds[tid] = s;
    __syncthreads();
    int t = s;
    for (int off = 1; off < 256; off <<= 1) {
        int add = (tid >= off) ? lds[tid - off] : 0;
        __syncthreads();
        t += add;
        lds[tid] = t;
        __syncthreads();
    }
    int run = t - s;
#pragma unroll
    for (int j = 0; j < 4; ++j) {
        int idx = base + j;
        if (idx < N_NODES) offs[idx] = run;
        run += v[j];
    }
    if (tid == 255) chunkSum[blockIdx.x] = t;
}

__global__ void k_scanB(const int* __restrict__ chunkSum, int* __restrict__ chunkOff,
                        int nc) {
    __shared__ int lds[64];
    int tid = threadIdx.x;
    int v = (tid < nc) ? chunkSum[tid] : 0;
    lds[tid] = v;
    __syncthreads();
    int t = v;
    for (int off = 1; off < 64; off <<= 1) {
        int add = (tid >= off) ? lds[tid - off] : 0;
        __syncthreads();
        t += add;
        lds[tid] = t;
        __syncthreads();
    }
    if (tid < nc) chunkOff[tid] = t - v;
}

__global__ void k_scanC(int* __restrict__ offs, const int* __restrict__ chunkOff) {
    int i = blockIdx.x * 256 + threadIdx.x;
    if (i < N_NODES) offs[i] += chunkOff[i >> 10];
}

__global__ void k_fill(const int* __restrict__ esrc, const int* __restrict__ edst,
                       const int* __restrict__ offs, int* __restrict__ fillp,
                       int* __restrict__ csrs) {
    int e = blockIdx.x * 256 + threadIdx.x;
    if (e >= N_EDGES) return;
    int s = esrc[e], d = edst[e];
    int p = atomicAdd(&fillp[d], 1);
    csrs[offs[d] + p] = s;
}

// ---------------- degree sort (counting sort, clamp 127) ----------------

__global__ void k_hist(const int* __restrict__ cnt, int* __restrict__ hist) {
    int i = blockIdx.x * 256 + threadIdx.x;
    if (i < N_NODES) atomicAdd(&hist[min(cnt[i], 127)], 1);
}

__global__ void k_scan128(const int* __restrict__ hist, int* __restrict__ binoff) {
    __shared__ int lds[128];
    int tid = threadIdx.x;
    int v = hist[tid];
    lds[tid] = v;
    __syncthreads();
    int t = v;
    for (int off = 1; off < 128; off <<= 1) {
        int add = (tid >= off) ? lds[tid - off] : 0;
        __syncthreads();
        t += add;
        lds[tid] = t;
        __syncthreads();
    }
    binoff[tid] = t - v; // exclusive
}

__global__ void k_scatter(const int* __restrict__ cnt, const int* __restrict__ binoff,
                          int* __restrict__ fill2, int* __restrict__ sorted) {
    int i = blockIdx.x * 256 + threadIdx.x;
    if (i >= N_NODES) return;
    int b = min(cnt[i], 127);
    int p = atomicAdd(&fill2[b], 1);
    sorted[binoff[b] + p] = i;
}

// ---------------- T[256,128] = relu(id_emb) @ Wn_bottom ----------------

__global__ __launch_bounds__(256) void k_idT(const float* __restrict__ id_emb,
                                             const float* __restrict__ Wn,
                                             float* __restrict__ T) {
    int t = threadIdx.x;
    int d = t & 127;
    int r = blockIdx.x * 2 + (t >> 7);
    float acc = 0.f;
    for (int k = 0; k < 128; ++k)
        acc = fmaf(fmaxf(id_emb[r * 128 + k], 0.f), Wn[(128 + k) * 128 + d], acc);
    T[r * 128 + d] = acc;
}

// ---------------- encoder: A = relu(posrelu @ Wn_top + T[id] + bn) ----------------

__global__ __launch_bounds__(256) void k_encoder(
    const float* __restrict__ pos, const int* __restrict__ idfeat,
    const float* __restrict__ Wp, const float* __restrict__ bp,
    const float* __restrict__ Wn, const float* __restrict__ bn,
    const float* __restrict__ T, float* __restrict__ A) {
    __shared__ float feat[64][128];
    __shared__ float posl[192];
    int t = threadIdx.x;
    int base = blockIdx.x * 64;
    if (t < 192) {
        int idx = base * 3 + t;
        posl[t] = (idx < N_NODES * 3) ? pos[idx] : 0.f;
    }
    __syncthreads();
    {
        int d = t & 127, rs = t >> 7;
        float w0 = Wp[d], w1 = Wp[128 + d], w2 = Wp[256 + d], bb = bp[d];
        for (int r = rs; r < 64; r += 2) {
            float v = 0.f;
            if (base + r < N_NODES) {
                float p0 = posl[r * 3], p1 = posl[r * 3 + 1], p2 = posl[r * 3 + 2];
                v = fmaxf(fmaf(p0, w0, fmaf(p1, w1, fmaf(p2, w2, bb))), 0.f);
            }
            feat[r][d] = v;
        }
    }
    __syncthreads();
    int c = (t & 31) * 4;
    int r0 = (t >> 5) * 8;
    float acc[8][4];
#pragma unroll
    for (int i = 0; i < 8; ++i)
#pragma unroll
        for (int j = 0; j < 4; ++j) acc[i][j] = 0.f;
#pragma unroll 2
    for (int k4 = 0; k4 < 32; ++k4) {
        int k = k4 * 4;
        float4 w0 = *(const float4*)&Wn[(k + 0) * 128 + c];
        float4 w1 = *(const float4*)&Wn[(k + 1) * 128 + c];
        float4 w2 = *(const float4*)&Wn[(k + 2) * 128 + c];
        float4 w3 = *(const float4*)&Wn[(k + 3) * 128 + c];
#pragma unroll
        for (int i = 0; i < 8; ++i) {
            float4 f = *(const float4*)&feat[r0 + i][k];
            acc[i][0] = fmaf(f.x, w0.x, fmaf(f.y, w1.x, fmaf(f.z, w2.x, fmaf(f.w, w3.x, acc[i][0]))));
            acc[i][1] = fmaf(f.x, w0.y, fmaf(f.y, w1.y, fmaf(f.z, w2.y, fmaf(f.w, w3.y, acc[i][1]))));
            acc[i][2] = fmaf(f.x, w0.z, fmaf(f.y, w1.z, fmaf(f.z, w2.z, fmaf(f.w, w3.z, acc[i][2]))));
            acc[i][3] = fmaf(f.x, w0.w, fmaf(f.y, w1.w, fmaf(f.z, w2.w, fmaf(f.w, w3.w, acc[i][3]))));
        }
    }
    float4 bb = *(const float4*)&bn[c];
#pragma unroll
    for (int i = 0; i < 8; ++i) {
        int node = base + r0 + i;
        if (node < N_NODES) {
            int id = idfeat[node];
            float4 tv = *(const float4*)&T[id * 128 + c];
            float4 o;
            o.x = fmaxf(acc[i][0] + bb.x + tv.x, 0.f);
            o.y = fmaxf(acc[i][1] + bb.y + tv.y, 0.f);
            o.z = fmaxf(acc[i][2] + bb.z + tv.z, 0.f);
            o.w = fmaxf(acc[i][3] + bb.w + tv.w, 0.f);
            *(float4*)&A[(size_t)node * 128 + c] = o;
        }
    }
}

// ---------------- dense GEMM: out[N,128] = H[N,128] @ W[128,128] ----------------

__global__ __launch_bounds__(256) void k_gemm(
    const float* __restrict__ H, const float* __restrict__ W, float* __restrict__ out) {
    __shared__ float feat[64][128];
    int t = threadIdx.x;
    int base = blockIdx.x * 64;
    {
        const float4* src = (const float4*)(H + (size_t)base * 128);
        float4* dstl = (float4*)&feat[0][0];
        int avail = N_NODES - base;
        if (avail >= 64) {
#pragma unroll
            for (int i = 0; i < 8; ++i) dstl[t + i * 256] = src[t + i * 256];
        } else {
            for (int i = t; i < 2048; i += 256) {
                int row = i >> 5;
                float4 v = make_float4(0.f, 0.f, 0.f, 0.f);
                if (row < avail) v = src[i];
                dstl[i] = v;
            }
        }
    }
    __syncthreads();
    int c = (t & 31) * 4;
    int r0 = (t >> 5) * 8;
    float acc[8][4];
#pragma unroll
    for (int i = 0; i < 8; ++i)
#pragma unroll
        for (int j = 0; j < 4; ++j) acc[i][j] = 0.f;
#pragma unroll 2
    for (int k4 = 0; k4 < 32; ++k4) {
        int k = k4 * 4;
        float4 w0 = *(const float4*)&W[(k + 0) * 128 + c];
        float4 w1 = *(const float4*)&W[(k + 1) * 128 + c];
        float4 w2 = *(const float4*)&W[(k + 2) * 128 + c];
        float4 w3 = *(const float4*)&W[(k + 3) * 128 + c];
#pragma unroll
        for (int i = 0; i < 8; ++i) {
            float4 f = *(const float4*)&feat[r0 + i][k];
            acc[i][0] = fmaf(f.x, w0.x, fmaf(f.y, w1.x, fmaf(f.z, w2.x, fmaf(f.w, w3.x, acc[i][0]))));
            acc[i][1] = fmaf(f.x, w0.y, fmaf(f.y, w1.y, fmaf(f.z, w2.y, fmaf(f.w, w3.y, acc[i][1]))));
            acc[i][2] = fmaf(f.x, w0.z, fmaf(f.y, w1.z, fmaf(f.z, w2.z, fmaf(f.w, w3.z, acc[i][2]))));
            acc[i][3] = fmaf(f.x, w0.w, fmaf(f.y, w1.w, fmaf(f.z, w2.w, fmaf(f.w, w3.w, acc[i][3]))));
        }
    }
#pragma unroll
    for (int i = 0; i < 8; ++i) {
        int node = base + r0 + i;
        if (node < N_NODES) {
            float4 o = make_float4(acc[i][0], acc[i][1], acc[i][2], acc[i][3]);
            *(float4*)&out[(size_t)node * 128 + c] = o;
        }
    }
}

// ---------------- GCN aggregate, true-XCD-column-sliced with work queues ----------
// Each block reads its REAL XCD id (HW_REG_XCC_ID) and claims 64-node tiles from
// the per-column-chunk queue matching its XCD (steals from others at the tail).
// XCD c's L2 then holds column slice c (50000*16*4B = 3.2MB < 4MiB) resident.
// Nodes are processed in degree-sorted order so the 16 nodes in a wave have
// near-equal edge counts (no divergence waste).

__global__ __launch_bounds__(256) void k_gather(
    const float* __restrict__ B, float* __restrict__ A,
    const int* __restrict__ offs, const int* __restrict__ cnt,
    const int* __restrict__ csrs, const float* __restrict__ dinv,
    const float* __restrict__ bias, const int* __restrict__ sorted,
    int* __restrict__ qhead) {
    unsigned xcc;
    asm volatile("s_getreg_b32 %0, hwreg(HW_REG_XCC_ID)" : "=s"(xcc));
    xcc &= 7;
    __shared__ int s_tile;
    const float4* B4 = (const float4*)B;
    int slot = threadIdx.x >> 2;  // 0..63 node slot
    int f4 = threadIdx.x & 3;
    for (int k = 0; k < 8; ++k) {
        int c = (xcc + k) & 7;
        int coff = c * 4 + f4;
        float4 bb = ((const float4*)bias)[coff];
        while (true) {
            __syncthreads();
            if (threadIdx.x == 0) s_tile = atomicAdd(&qhead[c], 1);
            __syncthreads();
            int seg = s_tile;
            if (seg >= NSEG) break;
            int gi = seg * 64 + slot;
            if (gi < N_NODES) {
                int node = sorted[gi];
                int start = offs[node];
                int cn = cnt[node];
                float di = dinv[node];
                float4 self = B4[(size_t)node * 32 + coff];
                float sw = di * di;
                float4 acc;
                acc.x = sw * self.x;
                acc.y = sw * self.y;
                acc.z = sw * self.z;
                acc.w = sw * self.w;
                for (int j = 0; j < cn; ++j) {
                    int s = csrs[start + j];
                    float w = di * dinv[s];
                    float4 v = B4[(size_t)s * 32 + coff];
                    acc.x = fmaf(w, v.x, acc.x);
                    acc.y = fmaf(w, v.y, acc.y);
                    acc.z = fmaf(w, v.z, acc.z);
                    acc.w = fmaf(w, v.w, acc.w);
                }
                acc.x = fmaxf(acc.x + bb.x, 0.f);
                acc.y = fmaxf(acc.y + bb.y, 0.f);
                acc.z = fmaxf(acc.z + bb.z, 0.f);
                acc.w = fmaxf(acc.w + bb.w, 0.f);
                ((float4*)A)[(size_t)node * 32 + coff] = acc;
            }
        }
    }
}

// ---------------- segment max (batch sorted; 32 nodes/thread, then one atomic)

__global__ void k_segmax(const float* __restrict__ A, float* __restrict__ gbuf,
                         const int* __restrict__ batch, int off) {
    int gid = blockIdx.x * blockDim.x + threadIdx.x;
    int d = gid & 127;
    int chunk = gid >> 7;
    int n0 = chunk * 32;
    if (n0 >= N_NODES) return;
    int nend = n0 + 32;
    if (nend > N_NODES) nend = N_NODES;
    float m = 0.f;
    int curg = batch[n0];
    for (int node = n0; node < nend; ++node) {
        int g = batch[node];
        if (g != curg) {
            atomicMax((int*)&gbuf[curg * GDIM + off + d], __float_as_int(m));
            curg = g;
            m = 0.f;
        }
        m = fmaxf(m, A[(size_t)node * 128 + d]);
    }
    atomicMax((int*)&gbuf[curg * GDIM + off + d], __float_as_int(m));
}

// ---------------- final: out[G,128] = gbuf[G,640] @ Wa[640,128] + ba

__global__ __launch_bounds__(128) void k_final(const float* __restrict__ gbuf,
                                               const float* __restrict__ Wa,
                                               const float* __restrict__ ba,
                                               float* __restrict__ out) {
    __shared__ float gr[GDIM];
    int g = blockIdx.x, t = threadIdx.x;
    for (int i = t; i < GDIM; i += 128) gr[i] = gbuf[g * GDIM + i];
    __syncthreads();
    float acc = ba[t];
    for (int k = 0; k < GDIM; ++k) acc = fmaf(gr[k], Wa[k * 128 + t], acc);
    out[g * 128 + t] = acc;
}

// ---------------- launch ----------------

extern "C" void kernel_launch(void* const* d_in, const int* in_sizes, int n_in,
                              void* d_out, int out_size, void* d_ws, size_t ws_size,
                              hipStream_t stream) {
    const float* pos    = (const float*)d_in[0];
    const int*   idfeat = (const int*)d_in[1];
    const int*   eidx   = (const int*)d_in[2];
    const int*   batch  = (const int*)d_in[3];
    const float* Wp     = (const float*)d_in[5];
    const float* bp     = (const float*)d_in[6];
    const float* id_emb = (const float*)d_in[7];
    const float* Wn     = (const float*)d_in[8];
    const float* bn     = (const float*)d_in[9];
    const float* convW  = (const float*)d_in[10];
    const float* convb  = (const float*)d_in[11];
    const float* Wa     = (const float*)d_in[12];
    const float* ba     = (const float*)d_in[13];
    float* out = (float*)d_out;

    const int* esrc = eidx;
    const int* edst = eidx + N_EDGES;

    char* w = (char*)d_ws;
    auto alloc = [&](size_t bytes) -> char* {
        char* p = w;
        w += (bytes + 255) & ~(size_t)255;
        return p;
    };
    float* A    = (float*)alloc((size_t)N_NODES * D * 4);
    float* B    = (float*)alloc((size_t)N_NODES * D * 4);
    float* dinv = (float*)alloc((size_t)N_NODES * 4);
    int*   cnt  = (int*)alloc((size_t)N_NODES * 4);
    int*   offs = (int*)alloc((size_t)(N_NODES + 1) * 4);
    int*   fillp= (int*)alloc((size_t)N_NODES * 4);
    int*   csum = (int*)alloc(64 * 4);
    int*   coff = (int*)alloc(64 * 4);
    int*   csrs = (int*)alloc((size_t)N_EDGES * 4);
    float* gbuf = (float*)alloc((size_t)NGRAPH * GDIM * 4);
    float* T    = (float*)alloc((size_t)256 * D * 4);
    int*   sorted = (int*)alloc((size_t)N_NODES * 4);
    int*   hist   = (int*)alloc(128 * 4);
    int*   binoff = (int*)alloc(128 * 4);
    int*   fill2  = (int*)alloc(128 * 4);
    int*   qheads = (int*)alloc(8 * NLAYER * 4);

    hipMemsetAsync(cnt, 0, (size_t)N_NODES * 4, stream);
    hipMemsetAsync(fillp, 0, (size_t)N_NODES * 4, stream);
    hipMemsetAsync(gbuf, 0, (size_t)NGRAPH * GDIM * 4, stream);
    hipMemsetAsync(hist, 0, 128 * 4, stream);
    hipMemsetAsync(fill2, 0, 128 * 4, stream);
    hipMemsetAsync(qheads, 0, 8 * NLAYER * 4, stream);

    k_count<<<(N_EDGES + 255) / 256, 256, 0, stream>>>(edst, cnt);
    k_dinv<<<(N_NODES + 255) / 256, 256, 0, stream>>>(cnt, dinv);

    int nchunk = (N_NODES + 1023) / 1024; // 49
    k_scanA<<<nchunk, 256, 0, stream>>>(cnt, offs, csum);
    k_scanB<<<1, 64, 0, stream>>>(csum, coff, nchunk);
    k_scanC<<<(N_NODES + 255) / 256, 256, 0, stream>>>(offs, coff);
    k_fill<<<(N_EDGES + 255) / 256, 256, 0, stream>>>(esrc, edst, offs, fillp, csrs);

    k_hist<<<(N_NODES + 255) / 256, 256, 0, stream>>>(cnt, hist);
    k_scan128<<<1, 128, 0, stream>>>(hist, binoff);
    k_scatter<<<(N_NODES + 255) / 256, 256, 0, stream>>>(cnt, binoff, fill2, sorted);

    k_idT<<<128, 256, 0, stream>>>(id_emb, Wn, T);
    k_encoder<<<(N_NODES + 63) / 64, 256, 0, stream>>>(pos, idfeat, Wp, bp, Wn, bn, T, A);

    int segmax_blocks = ((((N_NODES + 31) / 32) * 128) + 255) / 256;
    k_segmax<<<segmax_blocks, 256, 0, stream>>>(A, gbuf, batch, 0);

    for (int l = 0; l < NLAYER; ++l) {
        k_gemm<<<(N_NODES + 63) / 64, 256, 0, stream>>>(A, convW + (size_t)l * D * D, B);
        k_gather<<<2048, 256, 0, stream>>>(B, A, offs, cnt, csrs, dinv,
                                           convb + (size_t)l * D, sorted, qheads + l * 8);
        k_segmax<<<segmax_blocks, 256, 0, stream>>>(A, gbuf, batch, (l + 1) * D);
    }

    k_final<<<NGRAPH, 128, 0, stream>>>(gbuf, Wa, ba, out);
}

// Round 5
// 535.831 us; speedup vs baseline: 3.5020x; 3.5020x over previous
//
#include <hip/hip_runtime.h>

#define N_NODES 50000
#define N_EDGES 800000
#define D 128
#define NLAYER 4
#define NGRAPH 128
#define GDIM (5 * D) // 640

__device__ __forceinline__ float b2f(unsigned short u) {
    return __uint_as_float(((unsigned)u) << 16);
}
__device__ __forceinline__ unsigned short f2b(float f) {
    unsigned u = __float_as_uint(f);
    unsigned r = (u + 0x7fffu + ((u >> 16) & 1u)) >> 16; // round-to-nearest-even
    return (unsigned short)r;
}

// ---------------- CSR build ----------------

__global__ void k_count(const int* __restrict__ edst, int* __restrict__ cnt) {
    int e = blockIdx.x * 256 + threadIdx.x;
    if (e < N_EDGES) atomicAdd(&cnt[edst[e]], 1);
}

__global__ void k_dinv(const int* __restrict__ cnt, float* __restrict__ dinv) {
    int i = blockIdx.x * 256 + threadIdx.x;
    if (i < N_NODES) dinv[i] = 1.f / sqrtf((float)(cnt[i] + 1)); // +1 self-loop
}

// 2-level exclusive scan, chunk = 1024 elements (256 thr x 4)
__global__ void k_scanA(const int* __restrict__ cnt, int* __restrict__ offs,
                        int* __restrict__ chunkSum) {
    __shared__ int lds[256];
    int tid = threadIdx.x;
    int base = blockIdx.x * 1024 + tid * 4;
    int v[4];
    int s = 0;
#pragma unroll
    for (int j = 0; j < 4; ++j) {
        int idx = base + j;
        v[j] = (idx < N_NODES) ? cnt[idx] : 0;
        s += v[j];
    }
    lds[tid] = s;
    __syncthreads();
    int t = s;
    for (int off = 1; off < 256; off <<= 1) {
        int add = (tid >= off) ? lds[tid - off] : 0;
        __syncthreads();
        t += add;
        lds[tid] = t;
        __syncthreads();
    }
    int run = t - s;
#pragma unroll
    for (int j = 0; j < 4; ++j) {
        int idx = base + j;
        if (idx < N_NODES) offs[idx] = run;
        run += v[j];
    }
    if (tid == 255) chunkSum[blockIdx.x] = t;
}

__global__ void k_scanB(const int* __restrict__ chunkSum, int* __restrict__ chunkOff,
                        int nc) {
    __shared__ int lds[64];
    int tid = threadIdx.x;
    int v = (tid < nc) ? chunkSum[tid] : 0;
    lds[tid] = v;
    __syncthreads();
    int t = v;
    for (int off = 1; off < 64; off <<= 1) {
        int add = (tid >= off) ? lds[tid - off] : 0;
        __syncthreads();
        t += add;
        lds[tid] = t;
        __syncthreads();
    }
    if (tid < nc) chunkOff[tid] = t - v;
}

__global__ void k_scanC(int* __restrict__ offs, const int* __restrict__ chunkOff) {
    int i = blockIdx.x * 256 + threadIdx.x;
    if (i < N_NODES) offs[i] += chunkOff[i >> 10];
}

__global__ void k_fill(const int* __restrict__ esrc, const int* __restrict__ edst,
                       const int* __restrict__ offs, int* __restrict__ fillp,
                       int* __restrict__ csrs) {
    int e = blockIdx.x * 256 + threadIdx.x;
    if (e >= N_EDGES) return;
    int s = esrc[e], d = edst[e];
    int p = atomicAdd(&fillp[d], 1);
    csrs[offs[d] + p] = s;
}

// ---------------- T[256,128] = relu(id_emb) @ Wn_bottom ----------------

__global__ __launch_bounds__(256) void k_idT(const float* __restrict__ id_emb,
                                             const float* __restrict__ Wn,
                                             float* __restrict__ T) {
    int t = threadIdx.x;
    int d = t & 127;
    int r = blockIdx.x * 2 + (t >> 7);
    float acc = 0.f;
    for (int k = 0; k < 128; ++k)
        acc = fmaf(fmaxf(id_emb[r * 128 + k], 0.f), Wn[(128 + k) * 128 + d], acc);
    T[r * 128 + d] = acc;
}

// ---------------- encoder: A = relu(posrelu @ Wn_top + T[id] + bn) ----------------

__global__ __launch_bounds__(256) void k_encoder(
    const float* __restrict__ pos, const int* __restrict__ idfeat,
    const float* __restrict__ Wp, const float* __restrict__ bp,
    const float* __restrict__ Wn, const float* __restrict__ bn,
    const float* __restrict__ T, float* __restrict__ A) {
    __shared__ float feat[64][128];
    __shared__ float posl[192];
    int t = threadIdx.x;
    int base = blockIdx.x * 64;
    if (t < 192) {
        int idx = base * 3 + t;
        posl[t] = (idx < N_NODES * 3) ? pos[idx] : 0.f;
    }
    __syncthreads();
    {
        int d = t & 127, rs = t >> 7;
        float w0 = Wp[d], w1 = Wp[128 + d], w2 = Wp[256 + d], bb = bp[d];
        for (int r = rs; r < 64; r += 2) {
            float v = 0.f;
            if (base + r < N_NODES) {
                float p0 = posl[r * 3], p1 = posl[r * 3 + 1], p2 = posl[r * 3 + 2];
                v = fmaxf(fmaf(p0, w0, fmaf(p1, w1, fmaf(p2, w2, bb))), 0.f);
            }
            feat[r][d] = v;
        }
    }
    __syncthreads();
    int c = (t & 31) * 4;
    int r0 = (t >> 5) * 8;
    float acc[8][4];
#pragma unroll
    for (int i = 0; i < 8; ++i)
#pragma unroll
        for (int j = 0; j < 4; ++j) acc[i][j] = 0.f;
#pragma unroll 4
    for (int k4 = 0; k4 < 32; ++k4) {
        int k = k4 * 4;
        float4 w0 = *(const float4*)&Wn[(k + 0) * 128 + c];
        float4 w1 = *(const float4*)&Wn[(k + 1) * 128 + c];
        float4 w2 = *(const float4*)&Wn[(k + 2) * 128 + c];
        float4 w3 = *(const float4*)&Wn[(k + 3) * 128 + c];
#pragma unroll
        for (int i = 0; i < 8; ++i) {
            float4 f = *(const float4*)&feat[r0 + i][k];
            acc[i][0] = fmaf(f.x, w0.x, fmaf(f.y, w1.x, fmaf(f.z, w2.x, fmaf(f.w, w3.x, acc[i][0]))));
            acc[i][1] = fmaf(f.x, w0.y, fmaf(f.y, w1.y, fmaf(f.z, w2.y, fmaf(f.w, w3.y, acc[i][1]))));
            acc[i][2] = fmaf(f.x, w0.z, fmaf(f.y, w1.z, fmaf(f.z, w2.z, fmaf(f.w, w3.z, acc[i][2]))));
            acc[i][3] = fmaf(f.x, w0.w, fmaf(f.y, w1.w, fmaf(f.z, w2.w, fmaf(f.w, w3.w, acc[i][3]))));
        }
    }
    float4 bb = *(const float4*)&bn[c];
#pragma unroll
    for (int i = 0; i < 8; ++i) {
        int node = base + r0 + i;
        if (node < N_NODES) {
            int id = idfeat[node];
            float4 tv = *(const float4*)&T[id * 128 + c];
            float4 o;
            o.x = fmaxf(acc[i][0] + bb.x + tv.x, 0.f);
            o.y = fmaxf(acc[i][1] + bb.y + tv.y, 0.f);
            o.z = fmaxf(acc[i][2] + bb.z + tv.z, 0.f);
            o.w = fmaxf(acc[i][3] + bb.w + tv.w, 0.f);
            *(float4*)&A[(size_t)node * 128 + c] = o;
        }
    }
}

// ---------------- dense GEMM: Bb[N,128](bf16) = H[N,128] @ W[128,128] ----------------

__global__ __launch_bounds__(256) void k_gemm(
    const float* __restrict__ H, const float* __restrict__ W,
    unsigned short* __restrict__ Bb) {
    __shared__ float feat[64][128];
    int t = threadIdx.x;
    int base = blockIdx.x * 64;
    {
        const float4* src = (const float4*)(H + (size_t)base * 128);
        float4* dstl = (float4*)&feat[0][0];
        int avail = N_NODES - base;
        if (avail >= 64) {
#pragma unroll
            for (int i = 0; i < 8; ++i) dstl[t + i * 256] = src[t + i * 256];
        } else {
            for (int i = t; i < 2048; i += 256) {
                int row = i >> 5;
                float4 v = make_float4(0.f, 0.f, 0.f, 0.f);
                if (row < avail) v = src[i];
                dstl[i] = v;
            }
        }
    }
    __syncthreads();
    int c = (t & 31) * 4;
    int r0 = (t >> 5) * 8;
    float acc[8][4];
#pragma unroll
    for (int i = 0; i < 8; ++i)
#pragma unroll
        for (int j = 0; j < 4; ++j) acc[i][j] = 0.f;
#pragma unroll 4
    for (int k4 = 0; k4 < 32; ++k4) {
        int k = k4 * 4;
        float4 w0 = *(const float4*)&W[(k + 0) * 128 + c];
        float4 w1 = *(const float4*)&W[(k + 1) * 128 + c];
        float4 w2 = *(const float4*)&W[(k + 2) * 128 + c];
        float4 w3 = *(const float4*)&W[(k + 3) * 128 + c];
#pragma unroll
        for (int i = 0; i < 8; ++i) {
            float4 f = *(const float4*)&feat[r0 + i][k];
            acc[i][0] = fmaf(f.x, w0.x, fmaf(f.y, w1.x, fmaf(f.z, w2.x, fmaf(f.w, w3.x, acc[i][0]))));
            acc[i][1] = fmaf(f.x, w0.y, fmaf(f.y, w1.y, fmaf(f.z, w2.y, fmaf(f.w, w3.y, acc[i][1]))));
            acc[i][2] = fmaf(f.x, w0.z, fmaf(f.y, w1.z, fmaf(f.z, w2.z, fmaf(f.w, w3.z, acc[i][2]))));
            acc[i][3] = fmaf(f.x, w0.w, fmaf(f.y, w1.w, fmaf(f.z, w2.w, fmaf(f.w, w3.w, acc[i][3]))));
        }
    }
#pragma unroll
    for (int i = 0; i < 8; ++i) {
        int node = base + r0 + i;
        if (node < N_NODES) {
            ushort4 o;
            o.x = f2b(acc[i][0]);
            o.y = f2b(acc[i][1]);
            o.z = f2b(acc[i][2]);
            o.w = f2b(acc[i][3]);
            *(ushort4*)&Bb[(size_t)node * 128 + c] = o;
        }
    }
}

// ---------------- GCN aggregate (bf16 msgs, fp32 accumulate) ----------------
// A[i] = relu(sum_e dinv_i*dinv_src * B[src] + dinv_i^2 * B[i] + bias)
// 2 nodes/wave, 32 lanes/node, 8B (ushort4 = 4 bf16) per lane.

__global__ __launch_bounds__(256) void k_gather(
    const unsigned short* __restrict__ B, float* __restrict__ A,
    const int* __restrict__ offs, const int* __restrict__ cnt,
    const int* __restrict__ csrs, const float* __restrict__ dinv,
    const float* __restrict__ bias) {
    int lane = threadIdx.x & 63;
    int sub = lane >> 5;
    int l = lane & 31;
    int node = blockIdx.x * 8 + (threadIdx.x >> 6) * 2 + sub;
    if (node >= N_NODES) return;
    int start = offs[node];
    int c = cnt[node];
    float di = dinv[node];
    float sw = di * di;
    const ushort4* B4 = (const ushort4*)B; // 32 ushort4 per row
    ushort4 sv = B4[(size_t)node * 32 + l];
    float4 acc;
    acc.x = sw * b2f(sv.x);
    acc.y = sw * b2f(sv.y);
    acc.z = sw * b2f(sv.z);
    acc.w = sw * b2f(sv.w);
#pragma unroll 2
    for (int j = 0; j < c; ++j) {
        int s = csrs[start + j];
        float w = di * dinv[s];
        ushort4 v = B4[(size_t)s * 32 + l];
        acc.x = fmaf(w, b2f(v.x), acc.x);
        acc.y = fmaf(w, b2f(v.y), acc.y);
        acc.z = fmaf(w, b2f(v.z), acc.z);
        acc.w = fmaf(w, b2f(v.w), acc.w);
    }
    float4 bb = ((const float4*)bias)[l];
    acc.x = fmaxf(acc.x + bb.x, 0.f);
    acc.y = fmaxf(acc.y + bb.y, 0.f);
    acc.z = fmaxf(acc.z + bb.z, 0.f);
    acc.w = fmaxf(acc.w + bb.w, 0.f);
    ((float4*)(A + (size_t)node * 128))[l] = acc;
}

// ---------------- segment max (batch sorted; 32 nodes/thread, then one atomic)

__global__ void k_segmax(const float* __restrict__ A, float* __restrict__ gbuf,
                         const int* __restrict__ batch, int off) {
    int gid = blockIdx.x * blockDim.x + threadIdx.x;
    int d = gid & 127;
    int chunk = gid >> 7;
    int n0 = chunk * 32;
    if (n0 >= N_NODES) return;
    int nend = n0 + 32;
    if (nend > N_NODES) nend = N_NODES;
    float m = 0.f;
    int curg = batch[n0];
    for (int node = n0; node < nend; ++node) {
        int g = batch[node];
        if (g != curg) {
            atomicMax((int*)&gbuf[curg * GDIM + off + d], __float_as_int(m));
            curg = g;
            m = 0.f;
        }
        m = fmaxf(m, A[(size_t)node * 128 + d]);
    }
    atomicMax((int*)&gbuf[curg * GDIM + off + d], __float_as_int(m));
}

// ---------------- final: out[G,128] = gbuf[G,640] @ Wa[640,128] + ba

__global__ __launch_bounds__(128) void k_final(const float* __restrict__ gbuf,
                                               const float* __restrict__ Wa,
                                               const float* __restrict__ ba,
                                               float* __restrict__ out) {
    __shared__ float gr[GDIM];
    int g = blockIdx.x, t = threadIdx.x;
    for (int i = t; i < GDIM; i += 128) gr[i] = gbuf[g * GDIM + i];
    __syncthreads();
    float acc = ba[t];
    for (int k = 0; k < GDIM; ++k) acc = fmaf(gr[k], Wa[k * 128 + t], acc);
    out[g * 128 + t] = acc;
}

// ---------------- launch ----------------

extern "C" void kernel_launch(void* const* d_in, const int* in_sizes, int n_in,
                              void* d_out, int out_size, void* d_ws, size_t ws_size,
                              hipStream_t stream) {
    const float* pos    = (const float*)d_in[0];
    const int*   idfeat = (const int*)d_in[1];
    const int*   eidx   = (const int*)d_in[2];
    const int*   batch  = (const int*)d_in[3];
    const float* Wp     = (const float*)d_in[5];
    const float* bp     = (const float*)d_in[6];
    const float* id_emb = (const float*)d_in[7];
    const float* Wn     = (const float*)d_in[8];
    const float* bn     = (const float*)d_in[9];
    const float* convW  = (const float*)d_in[10];
    const float* convb  = (const float*)d_in[11];
    const float* Wa     = (const float*)d_in[12];
    const float* ba     = (const float*)d_in[13];
    float* out = (float*)d_out;

    const int* esrc = eidx;
    const int* edst = eidx + N_EDGES;

    char* w = (char*)d_ws;
    auto alloc = [&](size_t bytes) -> char* {
        char* p = w;
        w += (bytes + 255) & ~(size_t)255;
        return p;
    };
    float* A    = (float*)alloc((size_t)N_NODES * D * 4);
    unsigned short* Bb = (unsigned short*)alloc((size_t)N_NODES * D * 2);
    float* dinv = (float*)alloc((size_t)N_NODES * 4);
    int*   cnt  = (int*)alloc((size_t)N_NODES * 4);
    int*   offs = (int*)alloc((size_t)(N_NODES + 1) * 4);
    int*   fillp= (int*)alloc((size_t)N_NODES * 4);
    int*   csum = (int*)alloc(64 * 4);
    int*   coff = (int*)alloc(64 * 4);
    int*   csrs = (int*)alloc((size_t)N_EDGES * 4);
    float* gbuf = (float*)alloc((size_t)NGRAPH * GDIM * 4);
    float* T    = (float*)alloc((size_t)256 * D * 4);

    hipMemsetAsync(cnt, 0, (size_t)N_NODES * 4, stream);
    hipMemsetAsync(fillp, 0, (size_t)N_NODES * 4, stream);
    hipMemsetAsync(gbuf, 0, (size_t)NGRAPH * GDIM * 4, stream);

    k_count<<<(N_EDGES + 255) / 256, 256, 0, stream>>>(edst, cnt);
    k_dinv<<<(N_NODES + 255) / 256, 256, 0, stream>>>(cnt, dinv);

    int nchunk = (N_NODES + 1023) / 1024; // 49
    k_scanA<<<nchunk, 256, 0, stream>>>(cnt, offs, csum);
    k_scanB<<<1, 64, 0, stream>>>(csum, coff, nchunk);
    k_scanC<<<(N_NODES + 255) / 256, 256, 0, stream>>>(offs, coff);
    k_fill<<<(N_EDGES + 255) / 256, 256, 0, stream>>>(esrc, edst, offs, fillp, csrs);

    k_idT<<<128, 256, 0, stream>>>(id_emb, Wn, T);
    k_encoder<<<(N_NODES + 63) / 64, 256, 0, stream>>>(pos, idfeat, Wp, bp, Wn, bn, T, A);

    int segmax_blocks = ((((N_NODES + 31) / 32) * 128) + 255) / 256;
    k_segmax<<<segmax_blocks, 256, 0, stream>>>(A, gbuf, batch, 0);

    for (int l = 0; l < NLAYER; ++l) {
        k_gemm<<<(N_NODES + 63) / 64, 256, 0, stream>>>(A, convW + (size_t)l * D * D, Bb);
        k_gather<<<(N_NODES + 7) / 8, 256, 0, stream>>>(Bb, A, offs, cnt, csrs, dinv,
                                                        convb + (size_t)l * D);
        k_segmax<<<segmax_blocks, 256, 0, stream>>>(A, gbuf, batch, (l + 1) * D);
    }

    k_final<<<NGRAPH, 128, 0, stream>>>(gbuf, Wa, ba, out);
}

// Round 6
// 417.187 us; speedup vs baseline: 4.4979x; 1.2844x over previous
//
#include <hip/hip_runtime.h>

#define N_NODES 50000
#define N_EDGES 800000
#define D 128
#define NLAYER 4
#define NGRAPH 128
#define GDIM (5 * D) // 640

typedef __attribute__((ext_vector_type(8))) short bf16x8;
typedef __attribute__((ext_vector_type(4))) float f32x4;

__device__ __forceinline__ float b2f(unsigned short u) {
    return __uint_as_float(((unsigned)u) << 16);
}
__device__ __forceinline__ unsigned short f2b(float f) {
    unsigned u = __float_as_uint(f);
    unsigned r = (u + 0x7fffu + ((u >> 16) & 1u)) >> 16; // round-to-nearest-even
    return (unsigned short)r;
}

// ---------------- CSR build ----------------

__global__ void k_count(const int* __restrict__ edst, int* __restrict__ cnt) {
    int e = blockIdx.x * 256 + threadIdx.x;
    if (e < N_EDGES) atomicAdd(&cnt[edst[e]], 1);
}

__global__ void k_dinv(const int* __restrict__ cnt, float* __restrict__ dinv) {
    int i = blockIdx.x * 256 + threadIdx.x;
    if (i < N_NODES) dinv[i] = 1.f / sqrtf((float)(cnt[i] + 1)); // +1 self-loop
}

__global__ void k_scanA(const int* __restrict__ cnt, int* __restrict__ offs,
                        int* __restrict__ chunkSum) {
    __shared__ int lds[256];
    int tid = threadIdx.x;
    int base = blockIdx.x * 1024 + tid * 4;
    int v[4];
    int s = 0;
#pragma unroll
    for (int j = 0; j < 4; ++j) {
        int idx = base + j;
        v[j] = (idx < N_NODES) ? cnt[idx] : 0;
        s += v[j];
    }
    lds[tid] = s;
    __syncthreads();
    int t = s;
    for (int off = 1; off < 256; off <<= 1) {
        int add = (tid >= off) ? lds[tid - off] : 0;
        __syncthreads();
        t += add;
        lds[tid] = t;
        __syncthreads();
    }
    int run = t - s;
#pragma unroll
    for (int j = 0; j < 4; ++j) {
        int idx = base + j;
        if (idx < N_NODES) offs[idx] = run;
        run += v[j];
    }
    if (tid == 255) chunkSum[blockIdx.x] = t;
}

__global__ void k_scanB(const int* __restrict__ chunkSum, int* __restrict__ chunkOff,
                        int nc) {
    __shared__ int lds[64];
    int tid = threadIdx.x;
    int v = (tid < nc) ? chunkSum[tid] : 0;
    lds[tid] = v;
    __syncthreads();
    int t = v;
    for (int off = 1; off < 64; off <<= 1) {
        int add = (tid >= off) ? lds[tid - off] : 0;
        __syncthreads();
        t += add;
        lds[tid] = t;
        __syncthreads();
    }
    if (tid < nc) chunkOff[tid] = t - v;
}

__global__ void k_scanC(int* __restrict__ offs, const int* __restrict__ chunkOff) {
    int i = blockIdx.x * 256 + threadIdx.x;
    if (i < N_NODES) offs[i] += chunkOff[i >> 10];
}

__global__ void k_fill(const int* __restrict__ esrc, const int* __restrict__ edst,
                       const int* __restrict__ offs, int* __restrict__ fillp,
                       int* __restrict__ csrs) {
    int e = blockIdx.x * 256 + threadIdx.x;
    if (e >= N_EDGES) return;
    int s = esrc[e], d = edst[e];
    int p = atomicAdd(&fillp[d], 1);
    csrs[offs[d] + p] = s;
}

// ---------------- pack 5 weight matrices into MFMA B-frag layout (bf16) --------
// m=0: Wn_top (rows 0..127 of Wn), m=1..4: convW[l]
// Wpack[m][ct][kc][lane][j]: value = W[k][n], k = kc*32 + (lane>>4)*8 + j,
//                                    n = ct*16 + (lane&15)

__global__ void k_packW(const float* __restrict__ Wn, const float* __restrict__ convW,
                        unsigned short* __restrict__ Wpack) {
    int tid = blockIdx.x * 256 + threadIdx.x;
    if (tid >= 5 * 16384) return;
    int m = tid >> 14;
    int rem = tid & 16383;
    int ct = rem >> 11, kc = (rem >> 9) & 3, l = (rem >> 3) & 63, j = rem & 7;
    int k = kc * 32 + ((l >> 4) * 8) + j;
    int n = ct * 16 + (l & 15);
    const float* src = (m == 0) ? Wn : (convW + (size_t)(m - 1) * 16384);
    Wpack[tid] = f2b(src[k * 128 + n]);
}

// ---------------- T[256,128] = relu(id_emb) @ Wn_bottom ----------------

__global__ __launch_bounds__(256) void k_idT(const float* __restrict__ id_emb,
                                             const float* __restrict__ Wn,
                                             float* __restrict__ T) {
    int t = threadIdx.x;
    int d = t & 127;
    int r = blockIdx.x * 2 + (t >> 7);
    float acc = 0.f;
    for (int k = 0; k < 128; ++k)
        acc = fmaf(fmaxf(id_emb[r * 128 + k], 0.f), Wn[(128 + k) * 128 + d], acc);
    T[r * 128 + d] = acc;
}

// ---------------- MFMA encoder: A = relu(posrelu @ Wn_top + T[id] + bn) --------

__global__ __launch_bounds__(256) void k_encoder(
    const float* __restrict__ pos, const int* __restrict__ idfeat,
    const float* __restrict__ Wp, const float* __restrict__ bp,
    const unsigned short* __restrict__ WpackE, const float* __restrict__ bn,
    const float* __restrict__ T, float* __restrict__ A) {
    __shared__ unsigned short feat[64 * 128]; // 16KB, swizzled
    __shared__ float posl[192];
    int t = threadIdx.x;
    int base = blockIdx.x * 64;
    int avail = N_NODES - base;
    if (t < 192) {
        int idx = base * 3 + t;
        posl[t] = (idx < N_NODES * 3) ? pos[idx] : 0.f;
    }
    __syncthreads();
#pragma unroll
    for (int i = 0; i < 4; ++i) {
        int gid = t + i * 256;
        int row = gid >> 4, kg = gid & 15;
        unsigned short u[8];
        if (row < avail) {
            float p0 = posl[row * 3], p1 = posl[row * 3 + 1], p2 = posl[row * 3 + 2];
#pragma unroll
            for (int j = 0; j < 8; ++j) {
                int d = kg * 8 + j;
                float v = fmaf(p0, Wp[d], fmaf(p1, Wp[128 + d], fmaf(p2, Wp[256 + d], bp[d])));
                u[j] = f2b(fmaxf(v, 0.f));
            }
        } else {
#pragma unroll
            for (int j = 0; j < 8; ++j) u[j] = 0;
        }
        char* dst = (char*)feat + row * 256 + ((kg * 16) ^ ((row & 7) << 4));
        *(uint4*)dst = *(uint4*)u;
    }
    __syncthreads();
    int wid = t >> 6, l = t & 63;
    int r0 = wid * 16;
    f32x4 acc[8];
#pragma unroll
    for (int ct = 0; ct < 8; ++ct) acc[ct] = (f32x4){0.f, 0.f, 0.f, 0.f};
    const bf16x8* wp = (const bf16x8*)WpackE;
#pragma unroll
    for (int kc = 0; kc < 4; ++kc) {
        int row = r0 + (l & 15);
        const char* ap = (const char*)feat + row * 256 +
                         ((kc * 64 + ((l >> 4) * 16)) ^ ((row & 7) << 4));
        bf16x8 afrag = *(const bf16x8*)ap;
#pragma unroll
        for (int ct = 0; ct < 8; ++ct) {
            bf16x8 bfrag = wp[(ct * 4 + kc) * 64 + l];
            acc[ct] = __builtin_amdgcn_mfma_f32_16x16x32_bf16(afrag, bfrag, acc[ct], 0, 0, 0);
        }
    }
    int subrow = (l >> 4) * 4, col0 = l & 15;
    int ids[4];
#pragma unroll
    for (int i = 0; i < 4; ++i) {
        int node = base + r0 + subrow + i;
        ids[i] = (node < N_NODES) ? idfeat[node] : 0;
    }
#pragma unroll
    for (int ct = 0; ct < 8; ++ct) {
        int col = ct * 16 + col0;
        float bcol = bn[col];
#pragma unroll
        for (int i = 0; i < 4; ++i) {
            int node = base + r0 + subrow + i;
            if (node < N_NODES) {
                float v = acc[ct][i] + bcol + T[ids[i] * 128 + col];
                A[(size_t)node * 128 + col] = fmaxf(v, 0.f);
            }
        }
    }
}

// ---------------- MFMA GEMM: Bb[N,128](bf16) = H[N,128] @ W[128,128] ----------

__global__ __launch_bounds__(256) void k_gemm(
    const float* __restrict__ H, const unsigned short* __restrict__ WpackL,
    unsigned short* __restrict__ Bb) {
    __shared__ unsigned short feat[64 * 128]; // 16KB, swizzled
    int t = threadIdx.x;
    int base = blockIdx.x * 64;
    int avail = N_NODES - base;
#pragma unroll
    for (int i = 0; i < 4; ++i) {
        int gid = t + i * 256;
        int row = gid >> 4, kg = gid & 15;
        unsigned short u[8];
        if (row < avail) {
            float4 v0 = *(const float4*)&H[(size_t)(base + row) * 128 + kg * 8];
            float4 v1 = *(const float4*)&H[(size_t)(base + row) * 128 + kg * 8 + 4];
            u[0] = f2b(v0.x); u[1] = f2b(v0.y); u[2] = f2b(v0.z); u[3] = f2b(v0.w);
            u[4] = f2b(v1.x); u[5] = f2b(v1.y); u[6] = f2b(v1.z); u[7] = f2b(v1.w);
        } else {
#pragma unroll
            for (int j = 0; j < 8; ++j) u[j] = 0;
        }
        char* dst = (char*)feat + row * 256 + ((kg * 16) ^ ((row & 7) << 4));
        *(uint4*)dst = *(uint4*)u;
    }
    __syncthreads();
    int wid = t >> 6, l = t & 63;
    int r0 = wid * 16;
    f32x4 acc[8];
#pragma unroll
    for (int ct = 0; ct < 8; ++ct) acc[ct] = (f32x4){0.f, 0.f, 0.f, 0.f};
    const bf16x8* wp = (const bf16x8*)WpackL;
#pragma unroll
    for (int kc = 0; kc < 4; ++kc) {
        int row = r0 + (l & 15);
        const char* ap = (const char*)feat + row * 256 +
                         ((kc * 64 + ((l >> 4) * 16)) ^ ((row & 7) << 4));
        bf16x8 afrag = *(const bf16x8*)ap;
#pragma unroll
        for (int ct = 0; ct < 8; ++ct) {
            bf16x8 bfrag = wp[(ct * 4 + kc) * 64 + l];
            acc[ct] = __builtin_amdgcn_mfma_f32_16x16x32_bf16(afrag, bfrag, acc[ct], 0, 0, 0);
        }
    }
    int subrow = (l >> 4) * 4, col0 = l & 15;
#pragma unroll
    for (int ct = 0; ct < 8; ++ct) {
#pragma unroll
        for (int i = 0; i < 4; ++i) {
            int node = base + r0 + subrow + i;
            if (node < N_NODES)
                Bb[(size_t)node * 128 + ct * 16 + col0] = f2b(acc[ct][i]);
        }
    }
}

// ---------------- GCN aggregate (bf16 msgs, fp32 accumulate) ----------------

__global__ __launch_bounds__(256) void k_gather(
    const unsigned short* __restrict__ B, float* __restrict__ A,
    const int* __restrict__ offs, const int* __restrict__ cnt,
    const int* __restrict__ csrs, const float* __restrict__ dinv,
    const float* __restrict__ bias) {
    int lane = threadIdx.x & 63;
    int sub = lane >> 5;
    int l = lane & 31;
    int node = blockIdx.x * 8 + (threadIdx.x >> 6) * 2 + sub;
    if (node >= N_NODES) return;
    int start = offs[node];
    int c = cnt[node];
    float di = dinv[node];
    float sw = di * di;
    const ushort4* B4 = (const ushort4*)B; // 32 ushort4 per row
    ushort4 sv = B4[(size_t)node * 32 + l];
    float4 acc;
    acc.x = sw * b2f(sv.x);
    acc.y = sw * b2f(sv.y);
    acc.z = sw * b2f(sv.z);
    acc.w = sw * b2f(sv.w);
#pragma unroll 2
    for (int j = 0; j < c; ++j) {
        int s = csrs[start + j];
        float w = di * dinv[s];
        ushort4 v = B4[(size_t)s * 32 + l];
        acc.x = fmaf(w, b2f(v.x), acc.x);
        acc.y = fmaf(w, b2f(v.y), acc.y);
        acc.z = fmaf(w, b2f(v.z), acc.z);
        acc.w = fmaf(w, b2f(v.w), acc.w);
    }
    float4 bb = ((const float4*)bias)[l];
    acc.x = fmaxf(acc.x + bb.x, 0.f);
    acc.y = fmaxf(acc.y + bb.y, 0.f);
    acc.z = fmaxf(acc.z + bb.z, 0.f);
    acc.w = fmaxf(acc.w + bb.w, 0.f);
    ((float4*)(A + (size_t)node * 128))[l] = acc;
}

// ---------------- segment max (batch sorted; 32 nodes/thread, then one atomic)

__global__ void k_segmax(const float* __restrict__ A, float* __restrict__ gbuf,
                         const int* __restrict__ batch, int off) {
    int gid = blockIdx.x * blockDim.x + threadIdx.x;
    int d = gid & 127;
    int chunk = gid >> 7;
    int n0 = chunk * 32;
    if (n0 >= N_NODES) return;
    int nend = n0 + 32;
    if (nend > N_NODES) nend = N_NODES;
    float m = 0.f;
    int curg = batch[n0];
    for (int node = n0; node < nend; ++node) {
        int g = batch[node];
        if (g != curg) {
            atomicMax((int*)&gbuf[curg * GDIM + off + d], __float_as_int(m));
            curg = g;
            m = 0.f;
        }
        m = fmaxf(m, A[(size_t)node * 128 + d]);
    }
    atomicMax((int*)&gbuf[curg * GDIM + off + d], __float_as_int(m));
}

// ---------------- final: out[G,128] = gbuf[G,640] @ Wa[640,128] + ba

__global__ __launch_bounds__(128) void k_final(const float* __restrict__ gbuf,
                                               const float* __restrict__ Wa,
                                               const float* __restrict__ ba,
                                               float* __restrict__ out) {
    __shared__ float gr[GDIM];
    int g = blockIdx.x, t = threadIdx.x;
    for (int i = t; i < GDIM; i += 128) gr[i] = gbuf[g * GDIM + i];
    __syncthreads();
    float acc = ba[t];
    for (int k = 0; k < GDIM; ++k) acc = fmaf(gr[k], Wa[k * 128 + t], acc);
    out[g * 128 + t] = acc;
}

// ---------------- launch ----------------

extern "C" void kernel_launch(void* const* d_in, const int* in_sizes, int n_in,
                              void* d_out, int out_size, void* d_ws, size_t ws_size,
                              hipStream_t stream) {
    const float* pos    = (const float*)d_in[0];
    const int*   idfeat = (const int*)d_in[1];
    const int*   eidx   = (const int*)d_in[2];
    const int*   batch  = (const int*)d_in[3];
    const float* Wp     = (const float*)d_in[5];
    const float* bp     = (const float*)d_in[6];
    const float* id_emb = (const float*)d_in[7];
    const float* Wn     = (const float*)d_in[8];
    const float* bn     = (const float*)d_in[9];
    const float* convW  = (const float*)d_in[10];
    const float* convb  = (const float*)d_in[11];
    const float* Wa     = (const float*)d_in[12];
    const float* ba     = (const float*)d_in[13];
    float* out = (float*)d_out;

    const int* esrc = eidx;
    const int* edst = eidx + N_EDGES;

    char* w = (char*)d_ws;
    auto alloc = [&](size_t bytes) -> char* {
        char* p = w;
        w += (bytes + 255) & ~(size_t)255;
        return p;
    };
    float* A    = (float*)alloc((size_t)N_NODES * D * 4);
    unsigned short* Bb = (unsigned short*)alloc((size_t)N_NODES * D * 2);
    float* dinv = (float*)alloc((size_t)N_NODES * 4);
    int*   cnt  = (int*)alloc((size_t)N_NODES * 4);
    int*   offs = (int*)alloc((size_t)(N_NODES + 1) * 4);
    int*   fillp= (int*)alloc((size_t)N_NODES * 4);
    int*   csum = (int*)alloc(64 * 4);
    int*   coff = (int*)alloc(64 * 4);
    int*   csrs = (int*)alloc((size_t)N_EDGES * 4);
    float* gbuf = (float*)alloc((size_t)NGRAPH * GDIM * 4);
    float* T    = (float*)alloc((size_t)256 * D * 4);
    unsigned short* Wpack = (unsigned short*)alloc((size_t)5 * 16384 * 2);

    hipMemsetAsync(cnt, 0, (size_t)N_NODES * 4, stream);
    hipMemsetAsync(fillp, 0, (size_t)N_NODES * 4, stream);
    hipMemsetAsync(gbuf, 0, (size_t)NGRAPH * GDIM * 4, stream);

    k_count<<<(N_EDGES + 255) / 256, 256, 0, stream>>>(edst, cnt);
    k_dinv<<<(N_NODES + 255) / 256, 256, 0, stream>>>(cnt, dinv);

    int nchunk = (N_NODES + 1023) / 1024; // 49
    k_scanA<<<nchunk, 256, 0, stream>>>(cnt, offs, csum);
    k_scanB<<<1, 64, 0, stream>>>(csum, coff, nchunk);
    k_scanC<<<(N_NODES + 255) / 256, 256, 0, stream>>>(offs, coff);
    k_fill<<<(N_EDGES + 255) / 256, 256, 0, stream>>>(esrc, edst, offs, fillp, csrs);

    k_packW<<<(5 * 16384 + 255) / 256, 256, 0, stream>>>(Wn, convW, Wpack);
    k_idT<<<128, 256, 0, stream>>>(id_emb, Wn, T);
    k_encoder<<<(N_NODES + 63) / 64, 256, 0, stream>>>(pos, idfeat, Wp, bp, Wpack, bn, T, A);

    int segmax_blocks = ((((N_NODES + 31) / 32) * 128) + 255) / 256;
    k_segmax<<<segmax_blocks, 256, 0, stream>>>(A, gbuf, batch, 0);

    for (int l = 0; l < NLAYER; ++l) {
        k_gemm<<<(N_NODES + 63) / 64, 256, 0, stream>>>(A, Wpack + (size_t)(l + 1) * 16384, Bb);
        k_gather<<<(N_NODES + 7) / 8, 256, 0, stream>>>(Bb, A, offs, cnt, csrs, dinv,
                                                        convb + (size_t)l * D);
        k_segmax<<<segmax_blocks, 256, 0, stream>>>(A, gbuf, batch, (l + 1) * D);
    }

    k_final<<<NGRAPH, 128, 0, stream>>>(gbuf, Wa, ba, out);
}